// Round 3
// baseline (28.427 us; speedup 1.0000x reference)
//
#include <hip/hip_runtime.h>
#include <math.h>

#define NBLK 512
#define NTHR 256

constexpr float LOG_K_F = 2.7725887222397811f;   // log(16)
constexpr float LOG_EPS = -69.077552789821368f;  // log(1e-30)
constexpr float LOG_001 = -6.9077552789821368f;  // log(0.001)

struct BC {
    float ev_cat, ev_oth, qs, qo, eqs, eqo, evt_cat, evt_oth, C1, ct1e, klp;
    int t0;
};

__device__ __forceinline__ float lae_acc(float a, float b) {
    float m = fmaxf(a, b);
    return m + log1pf(expf(-fabsf(a - b)));
}

// Closed-form cosine-beta schedule constants (no table, no extra kernel).
// ac_raw(x) = cos^2(((x/1000)+0.008)/1.008 * pi/2) = sin^2(W*(1000-x)), W=pi/2016.
// log_cum[t] = log(ac_raw(t+1)/ac_raw(0)) for t<=998 (telescoped cumsum);
// t=999 is the only beta-clip (beta=0.999). Stable identities:
//   beta_t        = sin(W)*sin(W*(1999-2t)) / sin^2(W*(1000-t))
//   1 - cumalpha  = sin(W*(1999-t))*sin(W*(t+1)) / sin^2(W*1000)
__device__ __forceinline__ BC make_bc(int tb) {
    const float W = (float)(3.14159265358979323846 / 2016.0);
    const float s1000 = sinf(W * 1000.f);
    const float ls1000 = logf(s1000);
    const float inv2 = 1.f / (s1000 * s1000);

    const bool t999 = (tb == 999);
    const bool t0 = (tb == 0);
    const float ftb = (float)tb;

    // log_cum[tb]
    const int tbc = t999 ? 998 : tb;
    float ct = 2.f * (logf(sinf(W * (999.f - (float)tbc))) - ls1000);
    if (t999) ct += LOG_001;
    // log_1_min_cum[tb]  (formula also fine at 999: yields ~0, true value -2.4e-9)
    float dt = logf(sinf(W * (1999.f - ftb)) * sinf(W * (ftb + 1.f)) * inv2 + 1e-40f);
    // log_alpha[tb], log_1_min_alpha[tb]
    float at, btv;
    if (t999) {
        at = LOG_001;
        btv = logf(0.999f);
    } else {
        at = 2.f * (logf(sinf(W * (999.f - ftb))) - logf(sinf(W * (1000.f - ftb))));
        const float s0 = sinf(W * (1000.f - ftb));
        btv = logf(sinf(W) * sinf(W * (1999.f - 2.f * ftb)) / (s0 * s0) + 1e-40f);
    }
    // t-1 values
    float ct1 = 0.f, dt1 = 0.f;
    if (!t0) {
        ct1 = 2.f * (logf(sinf(W * (1000.f - ftb))) - ls1000);
        dt1 = logf(sinf(W * (2000.f - ftb)) * sinf(W * ftb) * inv2 + 1e-40f);
    }

    BC c;
    c.t0 = t0 ? 1 : 0;
    c.ev_cat = lae_acc(ct, dt - LOG_K_F);
    c.ev_oth = lae_acc(LOG_EPS + ct, dt - LOG_K_F);
    c.qs = lae_acc(at, btv - LOG_K_F);
    c.qo = lae_acc(LOG_EPS + at, btv - LOG_K_F);
    c.eqs = expf(c.qs);
    c.eqo = expf(c.qo);
    c.evt_cat = t0 ? 0.f : lae_acc(ct1, dt1 - LOG_K_F);
    c.evt_oth = t0 ? LOG_EPS : lae_acc(LOG_EPS + ct1, dt1 - LOG_K_F);
    c.C1 = t0 ? 0.f : expf(dt1 - LOG_K_F);
    c.ct1e = t0 ? 0.f : ct1;
    // prior-KL per-column constant (t = 999 values; cat-independent by symmetry)
    const float cT = 2.f * (logf(sinf(W * 1.f)) - ls1000) + LOG_001;
    const float dT = 0.f;  // log_1_min_cum[999] ~ -2.4e-9
    const float vc = lae_acc(cT, dT - LOG_K_F);
    const float vo = lae_acc(LOG_EPS + cT, dT - LOG_K_F);
    c.klp = expf(vc) * (vc + LOG_K_F) + 15.f * expf(vo) * (vo + LOG_K_F);
    return c;
}

// Per-column loss (validated math from R2, absmax 0.0)
__device__ __forceinline__ float column_loss(const float* ek, float slg, int cat,
                                             float u_cat, float umax, int kmx,
                                             const BC& c) {
    // gumbel-argmax: among k!=cat ev is identical -> winner is max-u
    const float e_c = -__logf(u_cat + 1e-30f) + 1e-30f;
    const float e_o = -__logf(umax + 1e-30f) + 1e-30f;
    const float v_c = c.ev_cat - __logf(e_c);
    const float v_o = c.ev_oth - __logf(e_o);
    const int samp = (v_c > v_o) ? cat : ((v_o > v_c) ? kmx : min(cat, kmx));

    // model posterior in exp space
    const float scale = __expf(c.ct1e - __logf(slg));
    float S_all = 0.f, sum_le = 0.f, le_cat = 0.f, le_samp = 0.f, ve_samp = 0.f;
#pragma unroll
    for (int k = 0; k < 16; ++k) {
        const float ve = ek[k] * scale + c.C1;
        const float le = __logf(ve);
        S_all += ve; sum_le += le;
        le_cat  = (k == cat)  ? le : le_cat;
        le_samp = (k == samp) ? le : le_samp;
        ve_samp = (k == samp) ? ve : ve_samp;
    }
    const float sum_m = c.eqo * (S_all - ve_samp) + c.eqs * ve_samp;
    const float lsem = __logf(sum_m);

    // true posterior: <=3 distinct values
    const bool eq = (cat == samp);
    const float q_c = eq ? c.qs : c.qo;
    const float w_s = eq ? 0.f : 1.f;
    const float n_o = eq ? 15.f : 14.f;
    const float a  = c.evt_cat + q_c;
    const float bs = c.evt_oth + c.qs;
    const float cc = c.evt_oth + c.qo;
    const float m  = fmaxf(a, fmaxf(bs, cc));
    const float ea = __expf(a - m), eb = __expf(bs - m), ecx = __expf(cc - m);
    const float lset = m + __logf(ea + w_s * eb + n_o * ecx);
    const float lt_c = a - lset, lt_s = bs - lset, lt_o = cc - lset;
    const float p_c = __expf(lt_c), p_s = __expf(lt_s), p_o = __expf(lt_o);

    const float sum_p_lt = p_c * lt_c + w_s * p_s * lt_s + n_o * p_o * lt_o;
    const float lm_cat  = le_cat + q_c - lsem;
    const float lm_samp = le_samp + c.qs - lsem;
    const float sum_lm_oth = (sum_le - le_cat - w_s * le_samp) + n_o * (c.qo - lsem);
    const float sum_p_lm = p_c * lm_cat + w_s * p_s * lm_samp + p_o * sum_lm_oth;
    const float kl  = sum_p_lt - sum_p_lm;
    const float nll = -lm_cat;
    return (c.t0 ? nll : kl) + c.klp;
}

// One fused kernel: 2 columns per thread (float2 loads), block reduce,
// last-block final reduce (rocPRIM-style counter pattern).
__global__ __launch_bounds__(NTHR) void fused_kernel(
        const int*   __restrict__ cats,     // [64,16,256]
        const float* __restrict__ logits,   // [64,256,256]
        const float* __restrict__ mnum,     // [64,8,256]
        const float* __restrict__ nnum,     // [64,8,256]
        const float* __restrict__ unoise,   // [64,256,256]
        const int*   __restrict__ tarr,     // [64]
        float*       __restrict__ partials, // [NBLK]
        unsigned*    __restrict__ counter,
        float*       __restrict__ out)
{
    const int g  = blockIdx.x * NTHR + threadIdx.x;  // 0..131071
    const int bi = g >> 7;                           // b*16 + i  (2 cols/thread)
    const int l0 = (g & 127) << 1;
    const int b  = bi >> 4;                          // block-uniform
    const BC c = make_bc(tarr[b]);

    const int2 cat2 = *reinterpret_cast<const int2*>(cats + (size_t)bi * 256 + l0);
    const size_t base = (size_t)bi * 4096 + l0;

    float ek0[16], ek1[16];
    float slg0 = 0.f, slg1 = 0.f, uc0 = 0.f, uc1 = 0.f, um0 = -1.f, um1 = -1.f;
    int km0 = 0, km1 = 0;
#pragma unroll
    for (int k = 0; k < 16; ++k) {
        const float2 u2 = *reinterpret_cast<const float2*>(unoise + base + (size_t)k * 256);
        const float2 g2 = *reinterpret_cast<const float2*>(logits + base + (size_t)k * 256);
        const float e0 = __expf(g2.x), e1 = __expf(g2.y);
        ek0[k] = e0; slg0 += e0;
        ek1[k] = e1; slg1 += e1;
        const bool ic0 = (k == cat2.x);
        uc0 = ic0 ? u2.x : uc0;
        const bool up0 = (!ic0) && (u2.x > um0);
        um0 = up0 ? u2.x : um0;  km0 = up0 ? k : km0;
        const bool ic1 = (k == cat2.y);
        uc1 = ic1 ? u2.y : uc1;
        const bool up1 = (!ic1) && (u2.y > um1);
        um1 = up1 ? u2.y : um1;  km1 = up1 ? k : km1;
    }

    float acc = column_loss(ek0, slg0, cat2.x, uc0, um0, km0, c)
              + column_loss(ek1, slg1, cat2.y, uc1, um1, km1, c);
    acc *= (0.5f / 64.0f);

    // numeric MSE: 131072 elems = 2 per thread for g < 65536 (blocks 0..255)
    if (g < 65536) {
        const float2 m2 = *reinterpret_cast<const float2*>(mnum + (size_t)2 * g);
        const float2 n2 = *reinterpret_cast<const float2*>(nnum + (size_t)2 * g);
        const float d0 = m2.x - n2.x, d1 = m2.y - n2.y;
        acc += (d0 * d0 + d1 * d1) * (0.5f / 131072.f);
    }

    // block reduction
    __shared__ float wsum[4];
    __shared__ int islast;
    for (int o = 32; o > 0; o >>= 1) acc += __shfl_down(acc, o, 64);
    const int wave = threadIdx.x >> 6, lane = threadIdx.x & 63;
    if (lane == 0) wsum[wave] = acc;
    __syncthreads();
    if (threadIdx.x == 0) {
        const float bsum = wsum[0] + wsum[1] + wsum[2] + wsum[3];
        partials[blockIdx.x] = bsum;
        __threadfence();
        const unsigned old = atomicAdd(counter, 1u);
        islast = (old == NBLK - 1) ? 1 : 0;
    }
    __syncthreads();
    if (islast) {   // block-uniform
        __threadfence();
        volatile const float* vp = partials;
        float v = vp[threadIdx.x] + vp[threadIdx.x + NTHR];
        for (int o = 32; o > 0; o >>= 1) v += __shfl_down(v, o, 64);
        if (lane == 0) wsum[wave] = v;
        __syncthreads();
        if (threadIdx.x == 0) out[0] = wsum[0] + wsum[1] + wsum[2] + wsum[3];
    }
}

extern "C" void kernel_launch(void* const* d_in, const int* in_sizes, int n_in,
                              void* d_out, int out_size, void* d_ws, size_t ws_size,
                              hipStream_t stream) {
    const int*   cats   = (const int*)  d_in[0];
    const float* logits = (const float*)d_in[1];
    const float* mnum   = (const float*)d_in[2];
    const float* nnum   = (const float*)d_in[3];
    const float* unoise = (const float*)d_in[4];
    const int*   tarr   = (const int*)  d_in[5];

    float*    partials = (float*)d_ws;
    unsigned* counter  = (unsigned*)((char*)d_ws + NBLK * sizeof(float));

    hipMemsetAsync(counter, 0, sizeof(unsigned), stream);
    fused_kernel<<<NBLK, NTHR, 0, stream>>>(cats, logits, mnum, nnum, unoise,
                                            tarr, partials, counter, (float*)d_out);
}